// Round 4
// baseline (179.720 us; speedup 1.0000x reference)
//
#include <hip/hip_runtime.h>
#include <hip/hip_fp16.h>
#include <math.h>

#define BB 128
#define HW 65536
#define OUT_B_STRIDE 196608   // 3*HW floats per batch in out

__device__ __forceinline__ float2 cadd(float2 a, float2 b){ return make_float2(a.x+b.x, a.y+b.y); }
__device__ __forceinline__ float2 csub(float2 a, float2 b){ return make_float2(a.x-b.x, a.y-b.y); }

// a * b  (INV=false)  or  a * conj(b)  (INV=true)
template<bool INV>
__device__ __forceinline__ float2 cmul_t(float2 a, float2 b){
  if (INV) return make_float2(a.x*b.x + a.y*b.y, a.y*b.x - a.x*b.y);
  return make_float2(a.x*b.x - a.y*b.y, a.x*b.y + a.y*b.x);
}

template<bool INV>
__device__ __forceinline__ void fft4(float2&a,float2&b,float2&c,float2&d){
  float2 t0 = cadd(a,c), t1 = csub(a,c);
  float2 t2 = cadd(b,d), t3 = csub(b,d);
  float2 t3r = INV ? make_float2(-t3.y, t3.x) : make_float2(t3.y, -t3.x);
  a = cadd(t0,t2);
  b = cadd(t1,t3r);
  c = csub(t0,t2);
  d = csub(t1,t3r);
}

// 16-point DFT, natural-in natural-out, exponent e^{-2pi i jq/16} (conj if INV).
template<bool INV>
__device__ __forceinline__ void fft16(float2 x[16]){
  #pragma unroll
  for (int j0=0;j0<4;++j0) fft4<INV>(x[j0], x[j0+4], x[j0+8], x[j0+12]);
  const float WR[10] = {1.f, 0.923879533f, 0.707106781f, 0.382683432f, 0.f,
                        0.f, -0.707106781f, 0.f, 0.f, -0.923879533f};
  const float WI[10] = {0.f, -0.382683432f, -0.707106781f, -0.923879533f, -1.f,
                        0.f, -0.707106781f, 0.f, 0.f, 0.382683432f};
  #pragma unroll
  for (int q0=1;q0<4;++q0)
    #pragma unroll
    for (int j0=1;j0<4;++j0){
      int k = j0*q0;
      x[j0+4*q0] = cmul_t<INV>(x[j0+4*q0], make_float2(WR[k], WI[k]));
    }
  #pragma unroll
  for (int q0=0;q0<4;++q0) fft4<INV>(x[4*q0], x[4*q0+1], x[4*q0+2], x[4*q0+3]);
  float2 t[16];
  #pragma unroll
  for (int q0=0;q0<4;++q0)
    #pragma unroll
    for (int q1=0;q1<4;++q1) t[q0+4*q1] = x[4*q0+q1];
  #pragma unroll
  for (int i=0;i<16;++i) x[i]=t[i];
}

// X[q] *= e^{sign * 2pi i * t*q / 256}, q=0..15, by register recurrence.
__device__ __forceinline__ void twiddle_mul(float2 X[16], int t, float sign){
  float sv, cv;
  __sincosf(sign * 0.024543692606170259968f * (float)t, &sv, &cv);  // 2pi/256
  float2 base = make_float2(cv, sv);
  float2 f = base;
  #pragma unroll
  for (int q=1;q<16;++q){
    X[q] = cmul_t<false>(X[q], f);
    f = cmul_t<false>(f, base);
  }
}

__device__ __forceinline__ uint pkh2(float2 v){
  __half2 h = __float22half2_rn(v);
  return *(uint*)&h;
}
__device__ __forceinline__ float2 uph2(uint u){
  __half2 h = *(__half2*)&u;
  return __half22float2(h);
}

// K1/K3 LDS: stride 272 (=16 mod 32) -> all patterns 2-way = free
union SharedRT {
  float xs[16*272];   // 17408 B
  uint  zu[16*272];
  float yb[16*272];
};

// ---------------- K1: row forward FFT (+ cidp prep in first 64 blocks) ----------------
// Storage: S[b][h][p] __half2, p = s*16 + k1 encodes w_freq = 16*k1 + s.
__global__ __launch_bounds__(256, 4) void k_row_fwd(const float* __restrict__ x,
                                                    __half2* __restrict__ S,
                                                    const int* __restrict__ cid,
                                                    unsigned char* __restrict__ cidp){
  __shared__ SharedRT sh;
  int tid = threadIdx.x;
  int t = tid & 15, r = tid >> 4;

  // cidp[p*256 + s*16 + k1] = cid[h2*256 + w2]
  if (blockIdx.x < 64){
    int g = (blockIdx.x*256 + tid) * 4;
    int p  = g >> 8;
    int s  = (g >> 4) & 15;
    int k1b = g & 15;
    int wfreq = 16*(p & 15) + (p >> 4);
    int w2 = (wfreq + 128) & 255;
    uchar4 v4;
    unsigned char* vp = (unsigned char*)&v4;
    #pragma unroll
    for (int i=0;i<4;++i){
      int h2 = (16*(k1b+i) + s + 128) & 255;
      vp[i] = (unsigned char)cid[h2*256 + w2];
    }
    *(uchar4*)(cidp + g) = v4;
  }

  const float4* xb = (const float4*)x + (size_t)blockIdx.x * 1024;
  #pragma unroll
  for (int k=0;k<4;++k){
    int i2 = tid + k*256;
    float4 v = xb[i2];
    int row = i2 >> 6, c4 = i2 & 63;
    *(float4*)&sh.xs[row*272 + c4*4] = v;
  }
  __syncthreads();
  float2 X[16];
  #pragma unroll
  for (int j=0;j<16;++j) X[j] = make_float2(sh.xs[r*272 + 16*j + t], 0.f);
  __syncthreads();                       // xs reads done; zu aliases
  fft16<false>(X);
  twiddle_mul(X, t, -1.f);
  #pragma unroll
  for (int q=0;q<16;++q) sh.zu[r*272 + q*17 + t] = pkh2(X[q]);
  __syncthreads();
  float2 Y[16];
  #pragma unroll
  for (int tt=0;tt<16;++tt) Y[tt] = uph2(sh.zu[r*272 + t*17 + tt]);
  fft16<false>(Y);                       // Y[k1] = X256[16k1 + s], s = t
  int row = blockIdx.x*16 + r;
  int b = row >> 8, h = row & 255;
  uint4* dst = (uint4*)(S + (size_t)b*HW + h*256 + t*16);
  #pragma unroll
  for (int k=0;k<4;++k){
    uint4 q;
    q.x = pkh2(Y[4*k+0]); q.y = pkh2(Y[4*k+1]);
    q.z = pkh2(Y[4*k+2]); q.w = pkh2(Y[4*k+3]);
    dst[k] = q;
  }
}

// ---------------- K2: column fwd + mask + column inv (in place) ----------------
__global__ __launch_bounds__(256, 4) void k_col(__half2* __restrict__ S,
                                                const unsigned char* __restrict__ cidp,
                                                const float* __restrict__ pi){
  __shared__ uint zu[16*274];   // stride 274 (=18 mod 32): 2-way = free
  __shared__ float sPI[64];
  int tid = threadIdx.x;
  int c = tid & 15, t = tid >> 4;
  int cg = blockIdx.x, b = blockIdx.y;
  if (tid < 64) sPI[tid] = pi[(((b + 64) & 127) << 6) + tid] * 0.25f;
  __half2* Sb = S + (size_t)b*HW;
  int p = cg*16 + c;
  float2 X[16];
  #pragma unroll
  for (int j=0;j<16;++j) X[j] = uph2(*(const uint*)&Sb[(16*j + t)*256 + p]);
  uint4 mq = *(const uint4*)(cidp + p*256 + t*16);
  fft16<false>(X);
  twiddle_mul(X, t, -1.f);
  #pragma unroll
  for (int q=0;q<16;++q) zu[c*274 + q*17 + t] = pkh2(X[q]);
  __syncthreads();                        // (1) also orders sPI
  float2 Y[16];
  #pragma unroll
  for (int tt=0;tt<16;++tt) Y[tt] = uph2(zu[c*274 + t*17 + tt]);
  fft16<false>(Y);                        // Y[k1] at h_freq = 16*k1 + s (s=t)
  const uint* mw = (const uint*)&mq;
  #pragma unroll
  for (int k1=0;k1<16;++k1){
    int cv = (mw[k1>>2] >> ((k1&3)*8)) & 255;
    float m = (cv < 64) ? sPI[cv] : 0.25f;
    Y[k1].x *= m; Y[k1].y *= m;
  }
  fft16<true>(Y);
  twiddle_mul(Y, t, +1.f);
  __syncthreads();                        // (2) phase-1 zu reads done
  #pragma unroll
  for (int u=0;u<16;++u) zu[c*274 + u*17 + t] = pkh2(Y[u]);
  __syncthreads();                        // (3)
  float2 R[16];
  #pragma unroll
  for (int k0=0;k0<16;++k0) R[k0] = uph2(zu[c*274 + t*17 + k0]);
  fft16<true>(R);
  #pragma unroll
  for (int j=0;j<16;++j)
    *(uint*)&Sb[(16*j + t)*256 + p] = pkh2(R[j]);
}

// ---------------- K3 (fused): row inverse + abs + finalize ----------------
__global__ __launch_bounds__(256, 4) void k_row_inv_fused(const __half2* __restrict__ S,
                                                          const float* __restrict__ x,
                                                          const float* __restrict__ pi,
                                                          float* __restrict__ out){
  __shared__ SharedRT sh;
  int tid = threadIdx.x;
  int s = tid & 15, r = tid >> 4;
  int slice = blockIdx.x, b = blockIdx.y;
  int h = slice*16 + r;
  const uint4* src = (const uint4*)(S + (size_t)b*HW + h*256 + s*16);
  float2 X[16];
  #pragma unroll
  for (int k=0;k<4;++k){
    uint4 q = src[k];
    X[4*k+0] = uph2(q.x); X[4*k+1] = uph2(q.y);
    X[4*k+2] = uph2(q.z); X[4*k+3] = uph2(q.w);
  }
  fft16<true>(X);
  twiddle_mul(X, s, +1.f);
  #pragma unroll
  for (int u=0;u<16;++u) sh.zu[r*272 + u*17 + s] = pkh2(X[u]);
  __syncthreads();
  float2 R[16];
  #pragma unroll
  for (int k0=0;k0<16;++k0) R[k0] = uph2(sh.zu[r*272 + s*17 + k0]);
  fft16<true>(R);
  __syncthreads();                          // zu reads done; yb aliases
  const float scale = 1.0f/16384.0f;        // 1/65536 * 4 (mask carried 1/4)
  #pragma unroll
  for (int j=0;j<16;++j)
    sh.yb[r*272 + 16*j + s] = sqrtf(R[j].x*R[j].x + R[j].y*R[j].y) * scale;
  __syncthreads();
  const float4* x4 = (const float4*)x;
  float4* o4 = (float4*)out;
  size_t xbase = (size_t)b*16384 + slice*1024;
  size_t obase = (size_t)b*49152 + slice*1024;
  #pragma unroll
  for (int k=0;k<4;++k){
    int i2 = tid + k*256;
    int rr = i2 >> 6, c4 = i2 & 63;
    float4 y = *(float4*)&sh.yb[rr*272 + c4*4];
    float4 xv = x4[xbase + i2];
    float4 df;
    df.x = fabsf(y.x - xv.x); df.y = fabsf(y.y - xv.y);
    df.z = fabsf(y.z - xv.z); df.w = fabsf(y.w - xv.w);
    o4[obase + i2]         = xv;
    o4[obase + i2 + 16384] = y;
    o4[obase + i2 + 32768] = df;
  }
  if (slice == 0 && b < 8){                 // PI tail: 8192 floats
    const float4* p4 = (const float4*)pi;
    o4[6291456 + b*256 + tid] = p4[b*256 + tid];
  }
}

// ---------------- K3 (fallback): row inverse + abs -> y into ch0 ----------------
__global__ __launch_bounds__(256, 4) void k_row_inv_stage(const __half2* __restrict__ S,
                                                          float* __restrict__ out){
  __shared__ SharedRT sh;
  int tid = threadIdx.x;
  int s = tid & 15, r = tid >> 4;
  int slice = blockIdx.x, b = blockIdx.y;
  int h = slice*16 + r;
  const uint4* src = (const uint4*)(S + (size_t)b*HW + h*256 + s*16);
  float2 X[16];
  #pragma unroll
  for (int k=0;k<4;++k){
    uint4 q = src[k];
    X[4*k+0] = uph2(q.x); X[4*k+1] = uph2(q.y);
    X[4*k+2] = uph2(q.z); X[4*k+3] = uph2(q.w);
  }
  fft16<true>(X);
  twiddle_mul(X, s, +1.f);
  #pragma unroll
  for (int u=0;u<16;++u) sh.zu[r*272 + u*17 + s] = pkh2(X[u]);
  __syncthreads();
  float2 R[16];
  #pragma unroll
  for (int k0=0;k0<16;++k0) R[k0] = uph2(sh.zu[r*272 + s*17 + k0]);
  fft16<true>(R);
  const float scale = 1.0f/16384.0f;
  float* o = out + (size_t)b*OUT_B_STRIDE + h*256;
  #pragma unroll
  for (int j=0;j<16;++j)
    o[16*j + s] = sqrtf(R[j].x*R[j].x + R[j].y*R[j].y) * scale;
}

// ---------------- K4 (fallback): finalize ----------------
__global__ __launch_bounds__(256) void k_final(const float* __restrict__ x,
                                               const float* __restrict__ pi,
                                               float* __restrict__ out) {
  int i = blockIdx.x * 256 + threadIdx.x;
  const float4* x4 = (const float4*)x;
  float4* o4 = (float4*)out;
  int b = i >> 14;
  int r = i & 16383;
  int ch0 = b * 49152 + r;
  float4 y  = o4[ch0];
  float4 xv = x4[i];
  float4 df;
  df.x = fabsf(y.x - xv.x);
  df.y = fabsf(y.y - xv.y);
  df.z = fabsf(y.z - xv.z);
  df.w = fabsf(y.w - xv.w);
  o4[ch0]         = xv;
  o4[ch0 + 16384] = y;
  o4[ch0 + 32768] = df;
  if (i < 2048) {
    const float4* p4 = (const float4*)pi;
    o4[6291456 + i] = p4[i];
  }
}

extern "C" void kernel_launch(void* const* d_in, const int* in_sizes, int n_in,
                              void* d_out, int out_size, void* d_ws, size_t ws_size,
                              hipStream_t stream) {
  const float* x  = (const float*)d_in[0];
  const float* pi = (const float*)d_in[1];
  const int*  cid = (const int*)d_in[2];
  float* out = (float*)d_out;
  (void)in_sizes; (void)n_in; (void)out_size;

  const size_t S_bytes = (size_t)BB * HW * sizeof(__half2);   // 32 MB
  const size_t cidp_bytes = 65536;

  if (ws_size >= S_bytes + cidp_bytes) {
    __half2* S = (__half2*)d_ws;
    unsigned char* cidp = (unsigned char*)d_ws + S_bytes;
    k_row_fwd<<<2048, 256, 0, stream>>>(x, S, cid, cidp);
    k_col<<<dim3(16, BB), 256, 0, stream>>>(S, cidp, pi);
    k_row_inv_fused<<<dim3(16, BB), 256, 0, stream>>>(S, x, pi, out);
  } else {
    __half2* S = (__half2*)out + (size_t)BB * HW;  // upper half of out as scratch
    unsigned char* cidp = (unsigned char*)d_ws;    // needs 64 KB
    k_row_fwd<<<2048, 256, 0, stream>>>(x, S, cid, cidp);
    k_col<<<dim3(16, BB), 256, 0, stream>>>(S, cidp, pi);
    k_row_inv_stage<<<dim3(16, BB), 256, 0, stream>>>(S, out);
    k_final<<<8192, 256, 0, stream>>>(x, pi, out);
  }
}